// Round 1
// baseline (36.671 us; speedup 1.0000x reference)
//
#include <hip/hip_runtime.h>
#include <hip/hip_bf16.h>

#define LSEQ   2048
#define DDIM   1024
#define TI     64
#define TJ     128
#define HALO   32
#define BK     64
#define NCHUNK (DDIM / BK)   // 16
#define LDST   72            // bf16 elems per LDS row: 64 + 8 pad (144B stride, conflict-free)
#define DECAY_F 0.8f

typedef __attribute__((ext_vector_type(8))) short  short8;
typedef __attribute__((ext_vector_type(4))) float  f32x4;

__device__ __forceinline__ unsigned short f2bf(float f) {
  // round-to-nearest-even f32 -> bf16 (inputs are finite random normals)
  unsigned u = __float_as_uint(f);
  u += 0x7fffu + ((u >> 16) & 1u);
  return (unsigned short)(u >> 16);
}

__global__ __launch_bounds__(512, 1)
void tsp_energy_kernel(const float* __restrict__ x1,
                       const float* __restrict__ x2,
                       float* __restrict__ out) {
  const int bid  = blockIdx.x;
  const int b    = bid >> 5;            // 32 i-tiles per batch
  const int i0   = (bid & 31) * TI;
  const int j0   = i0 - HALO;
  const int t    = threadIdx.x;
  const int wave = t >> 6;
  const int lane = t & 63;

  __shared__ unsigned short Al[2][TI][LDST];
  __shared__ unsigned short Bl[2][TJ][LDST];
  __shared__ float nsq1p[512], nsq2p[512];
  __shared__ float inv1[TI], inv2[TJ];
  __shared__ float outAcc[TI][2];

  // ---- staging assignment (row fixed per thread across all K-chunks) ----
  const int arow = t >> 3;              // 0..63, 8 threads/row, 8 floats each
  const int ac0  = (t & 7) * 8;
  const int brow = t >> 2;              // 0..127, 4 threads/row, 16 floats each
  const int bc0  = (t & 3) * 16;
  const int jrow = j0 + brow;
  const bool jok = (jrow >= 0) && (jrow < LSEQ);

  const float* ap = x1 + ((size_t)b * LSEQ + (i0 + arow)) * DDIM + ac0;
  const float* bp = jok ? (x2 + ((size_t)b * LSEQ + jrow) * DDIM + bc0) : x2;

  float ar[8], br[16];
  float nsqa = 0.f, nsqb = 0.f;

  // ---- MFMA wave tiling: wave -> (M-tile mt of 4, N-half ng of 2) ----
  const int mt  = wave >> 1;
  const int ng  = wave & 1;
  const int l15 = lane & 15;
  const int kof = (lane >> 4) * 8;
  f32x4 acc[4];
  #pragma unroll
  for (int n = 0; n < 4; ++n) acc[n] = (f32x4){0.f, 0.f, 0.f, 0.f};

  auto load_regs = [&](int c) {
    const float* pa = ap + c * BK;
    f32x4 a0 = *(const f32x4*)(pa + 0);
    f32x4 a1 = *(const f32x4*)(pa + 4);
    #pragma unroll
    for (int j = 0; j < 4; ++j) { ar[j] = a0[j]; ar[4 + j] = a1[j]; }
    if (jok) {
      const float* pb = bp + c * BK;
      f32x4 b0 = *(const f32x4*)(pb + 0);
      f32x4 b1 = *(const f32x4*)(pb + 4);
      f32x4 b2 = *(const f32x4*)(pb + 8);
      f32x4 b3 = *(const f32x4*)(pb + 12);
      #pragma unroll
      for (int j = 0; j < 4; ++j) {
        br[j] = b0[j]; br[4 + j] = b1[j]; br[8 + j] = b2[j]; br[12 + j] = b3[j];
      }
    } else {
      #pragma unroll
      for (int j = 0; j < 16; ++j) br[j] = 0.f;
    }
  };

  auto write_lds = [&](int buf) {
    short8 av;
    #pragma unroll
    for (int j = 0; j < 8; ++j) { float v = ar[j]; nsqa += v * v; av[j] = (short)f2bf(v); }
    *(short8*)&Al[buf][arow][ac0] = av;
    short8 bv0, bv1;
    #pragma unroll
    for (int j = 0; j < 8; ++j) { float v = br[j];     nsqb += v * v; bv0[j] = (short)f2bf(v); }
    #pragma unroll
    for (int j = 0; j < 8; ++j) { float v = br[8 + j]; nsqb += v * v; bv1[j] = (short)f2bf(v); }
    *(short8*)&Bl[buf][brow][bc0]     = bv0;
    *(short8*)&Bl[buf][brow][bc0 + 8] = bv1;
  };

  auto mfma_step = [&](int buf) {
    const unsigned short* abase = &Al[buf][mt * 16 + l15][kof];
    short8 af0 = *(const short8*)(abase);
    short8 af1 = *(const short8*)(abase + 32);
    #pragma unroll
    for (int n = 0; n < 4; ++n) {
      const unsigned short* bbase = &Bl[buf][(ng * 4 + n) * 16 + l15][kof];
      short8 bf0 = *(const short8*)(bbase);
      short8 bf1 = *(const short8*)(bbase + 32);
      acc[n] = __builtin_amdgcn_mfma_f32_16x16x32_bf16(af0, bf0, acc[n], 0, 0, 0);
      acc[n] = __builtin_amdgcn_mfma_f32_16x16x32_bf16(af1, bf1, acc[n], 0, 0, 0);
    }
  };

  // ---- main K-loop: double-buffered, reg-prefetch, one barrier per chunk ----
  load_regs(0);
  write_lds(0);
  for (int c = 0; c < NCHUNK; ++c) {
    if (c + 1 < NCHUNK) load_regs(c + 1);   // issue next-chunk loads early
    __syncthreads();                        // buf[c&1] writes visible
    mfma_step(c & 1);
    if (c + 1 < NCHUNK) write_lds((c + 1) & 1);
  }

  // ---- norms (fp32, accumulated during staging) ----
  nsq1p[t] = nsqa;
  nsq2p[t] = nsqb;
  __syncthreads();
  if (t < TI) {
    float s = 0.f;
    #pragma unroll
    for (int k = 0; k < 8; ++k) s += nsq1p[t * 8 + k];
    inv1[t] = 1.f / fmaxf(sqrtf(s), 1e-8f);
  } else if (t < TI + TJ) {
    int r = t - TI;
    float s = 0.f;
    #pragma unroll
    for (int k = 0; k < 4; ++k) s += nsq2p[r * 4 + k];
    inv2[r] = 1.f / fmaxf(sqrtf(s), 1e-8f);
  }
  __syncthreads();

  // ---- epilogue: weight, normalize (x2 side), reduce over columns ----
  float rowsum[4] = {0.f, 0.f, 0.f, 0.f};
  #pragma unroll
  for (int n = 0; n < 4; ++n) {
    int tj = (ng * 4 + n) * 16 + l15;
    float iv2 = inv2[tj];
    #pragma unroll
    for (int r = 0; r < 4; ++r) {
      int ti = mt * 16 + (lane >> 4) * 4 + r;
      float off = fabsf((float)(tj - HALO - ti));
      rowsum[r] += __expf(-DECAY_F * off) * iv2 * acc[n][r];
    }
  }
  #pragma unroll
  for (int m = 1; m <= 8; m <<= 1) {
    #pragma unroll
    for (int r = 0; r < 4; ++r) rowsum[r] += __shfl_xor(rowsum[r], m, 64);
  }
  if (l15 == 0) {
    #pragma unroll
    for (int r = 0; r < 4; ++r) outAcc[mt * 16 + (lane >> 4) * 4 + r][ng] = rowsum[r];
  }
  __syncthreads();

  if (t < TI) {
    const int i  = i0 + t;
    const float A  = __expf(-DECAY_F);
    const float a1 = __expf(-DECAY_F * (float)(i + 1));
    const float a2 = __expf(-DECAY_F * (float)(LSEQ - i));
    // W_i = sum_j a^|i-j| over ALL j (exact closed form)
    const float Wi = (1.f - a1 + A - a2) / (1.f - A);
    out[(size_t)b * LSEQ + i] = Wi - inv1[t] * (outAcc[t][0] + outAcc[t][1]);
  }
}

extern "C" void kernel_launch(void* const* d_in, const int* in_sizes, int n_in,
                              void* d_out, int out_size, void* d_ws, size_t ws_size,
                              hipStream_t stream) {
  const float* x1 = (const float*)d_in[0];
  const float* x2 = (const float*)d_in[1];
  float* out = (float*)d_out;
  dim3 grid(8 * (LSEQ / TI));   // 256 WGs = 1 per CU
  dim3 block(512);
  tsp_energy_kernel<<<grid, block, 0, stream>>>(x1, x2, out);
}